// Round 1
// baseline (339.856 us; speedup 1.0000x reference)
//
#include <hip/hip_runtime.h>

typedef unsigned short u16;
typedef unsigned int u32;

using short8 = __attribute__((ext_vector_type(8))) short;
using f32x4  = __attribute__((ext_vector_type(4))) float;

#define SSEQ 512
#define BB   16
#define DD   256
#define G4   256      // 4*SS
#define SSZ  64       // SS
#define VV   10000
#define VPAD 10112    // 79*128
#define MALL 8192     // BB*SSEQ

// ---- ws layout (bytes) ----
#define OFF_XHI   0u
#define OFF_XLO   4194304u
#define OFF_WHI   8388608u
#define OFF_WLO   8519680u
#define OFF_WSY   8650752u
#define OFF_XPROJ 9945088u
#define OFF_HS    18333696u

__device__ __forceinline__ u16 f2bf(float f) {
  u32 u = __float_as_uint(f);
  u32 r = (u + 0x7fffu + ((u >> 16) & 1u)) >> 16;
  return (u16)r;
}
__device__ __forceinline__ float bf2f(u16 h) {
  return __uint_as_float(((u32)h) << 16);
}
__device__ __forceinline__ float sigm(float x) {
  float e = exp2f(-1.442695041f * x);
  return __builtin_amdgcn_rcpf(1.f + e);
}
__device__ __forceinline__ float tanh_fast(float x) {
  float xc = fminf(fmaxf(x, -20.f), 20.f);
  float z = exp2f(2.885390082f * xc);
  return (z - 1.f) * __builtin_amdgcn_rcpf(z + 1.f);
}

// ---------------- K0: fp32 -> bf16 (hi/lo split for x, Wxs; padded bf16 Wsy) ----
#define NX 2097152
#define NW 65536
#define NP 647168   // VPAD*64
__global__ void k0_convert(const float* __restrict__ x, const float* __restrict__ Wxs,
                           const float* __restrict__ Wsy,
                           u16* __restrict__ xhi, u16* __restrict__ xlo,
                           u16* __restrict__ whi, u16* __restrict__ wlo,
                           u16* __restrict__ wsyb) {
  int i = blockIdx.x * 256 + threadIdx.x;
  if (i < NX) {
    float v = x[i]; u16 h = f2bf(v);
    xhi[i] = h; xlo[i] = f2bf(v - bf2f(h));
  } else if (i < NX + NW) {
    int j = i - NX;
    float v = Wxs[j]; u16 h = f2bf(v);
    whi[j] = h; wlo[j] = f2bf(v - bf2f(h));
  } else if (i < NX + NW + NP) {
    int j = i - NX - NW;
    wsyb[j] = (j < VV * SSZ) ? f2bf(Wsy[j]) : (u16)0;
  }
}

// ---------------- K1: xproj = x @ Wxs^T + b   (double-bf16 MFMA, fp32 out) ------
// M=8192, N=256, K=256. Tile 128x128, 4 waves (2x2), grid 64*2.
__global__ __launch_bounds__(256) void k1_xproj(
    const u16* __restrict__ xhi, const u16* __restrict__ xlo,
    const u16* __restrict__ whi, const u16* __restrict__ wlo,
    const float* __restrict__ bias, float* __restrict__ xproj) {
  int bid = blockIdx.x;
  int mb = bid >> 1, nb = bid & 1;
  int tid = threadIdx.x, l = tid & 63, wid = tid >> 6;
  int wm = wid >> 1, wv = wid & 1;
  int m0 = mb * 128 + wm * 64, n0 = nb * 128 + wv * 64;
  int lr = l & 15, lg = l >> 4;

  f32x4 acc[4][4];
#pragma unroll
  for (int a = 0; a < 4; a++)
#pragma unroll
    for (int bq = 0; bq < 4; bq++) acc[a][bq] = (f32x4){0.f, 0.f, 0.f, 0.f};

#pragma unroll
  for (int p = 0; p < 3; p++) {
    const u16* A = (p == 1) ? xlo : xhi;
    const u16* B = (p == 2) ? wlo : whi;
#pragma unroll
    for (int ks = 0; ks < 8; ks++) {
      short8 af[4], bf_[4];
#pragma unroll
      for (int fm = 0; fm < 4; fm++)
        af[fm] = *(const short8*)(A + (size_t)(m0 + fm * 16 + lr) * 256 + ks * 32 + lg * 8);
#pragma unroll
      for (int fv = 0; fv < 4; fv++)
        bf_[fv] = *(const short8*)(B + (size_t)(n0 + fv * 16 + lr) * 256 + ks * 32 + lg * 8);
#pragma unroll
      for (int fm = 0; fm < 4; fm++)
#pragma unroll
        for (int fv = 0; fv < 4; fv++)
          acc[fm][fv] = __builtin_amdgcn_mfma_f32_16x16x32_bf16(af[fm], bf_[fv], acc[fm][fv], 0, 0, 0);
    }
  }
#pragma unroll
  for (int fv = 0; fv < 4; fv++) {
    int j = n0 + fv * 16 + lr;
    float bj = bias[j];
#pragma unroll
    for (int fm = 0; fm < 4; fm++)
#pragma unroll
      for (int r = 0; r < 4; r++) {
        int m = m0 + fm * 16 + lg * 4 + r;
        xproj[(size_t)m * 256 + j] = acc[fm][fv][r] + bj;
      }
  }
}

// ---------------- K2: serial LSTM scan. 16 blocks (one per batch) x 256 thr ----
__global__ __launch_bounds__(256, 1) void k2_scan(
    const float* __restrict__ xproj, const float* __restrict__ Wss,
    const float* __restrict__ Wssb, u16* __restrict__ hsb) {
  __shared__ float lds[2][256];
  int b = blockIdx.x, tid = threadIdx.x, l = tid & 63;

  // Wss row for output j=tid, pinned in VGPRs
  float wreg[64];
  const float4* wrow = (const float4*)(Wss + (size_t)tid * 64);
#pragma unroll
  for (int q = 0; q < 16; q++) {
    float4 w4 = wrow[q];
    wreg[4 * q + 0] = w4.x; wreg[4 * q + 1] = w4.y;
    wreg[4 * q + 2] = w4.z; wreg[4 * q + 3] = w4.w;
  }
  float bj = Wssb[tid];

  float hsg[64];
#pragma unroll
  for (int k = 0; k < 64; k++) hsg[k] = 0.f;
  float c = 0.f;

  const float* xpb = xproj + (size_t)b * SSEQ * 256 + tid;
  u16* hout = hsb + (size_t)b * SSEQ * 64 + l;
  float xp_next = xpb[0];

  for (int t = 0; t < SSEQ; t++) {
    float xp = xp_next;
    if (t + 1 < SSEQ) xp_next = xpb[(size_t)(t + 1) * 256];

    float a0 = xp + bj, a1 = 0.f, a2 = 0.f, a3 = 0.f;
#pragma unroll
    for (int k = 0; k < 16; k++) {
      a0 = fmaf(hsg[k],      wreg[k],      a0);
      a1 = fmaf(hsg[16 + k], wreg[16 + k], a1);
      a2 = fmaf(hsg[32 + k], wreg[32 + k], a2);
      a3 = fmaf(hsg[48 + k], wreg[48 + k], a3);
    }
    int buf = t & 1;
    lds[buf][tid] = (a0 + a1) + (a2 + a3);
    // LDS-visibility barrier WITHOUT vmcnt drain (keeps xp prefetch in flight)
    asm volatile("s_waitcnt lgkmcnt(0)\n\ts_barrier" ::: "memory");

    float fr = lds[buf][l];
    float ir = lds[buf][64 + l];
    float gr = lds[buf][128 + l];
    float orr = lds[buf][192 + l];

    float fg = sigm(fr), ig = sigm(ir), og = sigm(orr);
    float gg = tanh_fast(gr);
    c = fmaf(c, fg, ig * gg);
    float hn = og * c;   // faithful to reference: no tanh(c)

    if (tid < 64) hout[(size_t)t * 64] = f2bf(hn);

#pragma unroll
    for (int k = 0; k < 64; k++)
      hsg[k] = __uint_as_float(__builtin_amdgcn_readlane(__float_as_uint(hn), k));
  }
}

// ---------------- K3: y = hs @ Wsy^T + b   (bf16 MFMA, no LDS, fp32 out) -------
// M=8192, N=10000(pad 10112), K=64. Tile 128x128, grid 64*79.
__global__ __launch_bounds__(256) void k3_y(
    const u16* __restrict__ hsb, const u16* __restrict__ wsyb,
    const float* __restrict__ bias, float* __restrict__ y) {
  int bid = blockIdx.x;
  int mb = bid / 79, vb = bid - mb * 79;
  int tid = threadIdx.x, l = tid & 63, wid = tid >> 6;
  int wm = wid >> 1, wv = wid & 1;
  int m0 = mb * 128 + wm * 64, v0 = vb * 128 + wv * 64;
  int lr = l & 15, lg = l >> 4;

  f32x4 acc[4][4];
#pragma unroll
  for (int a = 0; a < 4; a++)
#pragma unroll
    for (int bq = 0; bq < 4; bq++) acc[a][bq] = (f32x4){0.f, 0.f, 0.f, 0.f};

#pragma unroll
  for (int ks = 0; ks < 2; ks++) {
    short8 af[4], bf_[4];
#pragma unroll
    for (int fm = 0; fm < 4; fm++)
      af[fm] = *(const short8*)(hsb + (size_t)(m0 + fm * 16 + lr) * 64 + ks * 32 + lg * 8);
#pragma unroll
    for (int fv = 0; fv < 4; fv++)
      bf_[fv] = *(const short8*)(wsyb + (size_t)(v0 + fv * 16 + lr) * 64 + ks * 32 + lg * 8);
#pragma unroll
    for (int fm = 0; fm < 4; fm++)
#pragma unroll
      for (int fv = 0; fv < 4; fv++)
        acc[fm][fv] = __builtin_amdgcn_mfma_f32_16x16x32_bf16(af[fm], bf_[fv], acc[fm][fv], 0, 0, 0);
  }

#pragma unroll
  for (int fv = 0; fv < 4; fv++) {
    int v = v0 + fv * 16 + lr;
    bool ok = (v < VV);
    float bv = ok ? bias[v] : 0.f;
#pragma unroll
    for (int fm = 0; fm < 4; fm++)
#pragma unroll
      for (int r = 0; r < 4; r++) {
        int m = m0 + fm * 16 + lg * 4 + r;
        if (ok) y[(size_t)m * (size_t)VV + v] = acc[fm][fv][r] + bv;
      }
  }
}

extern "C" void kernel_launch(void* const* d_in, const int* in_sizes, int n_in,
                              void* d_out, int out_size, void* d_ws, size_t ws_size,
                              hipStream_t stream) {
  const float* x     = (const float*)d_in[0];
  const float* Wxs_w = (const float*)d_in[1];
  const float* Wxs_b = (const float*)d_in[2];
  const float* Wss_w = (const float*)d_in[3];
  const float* Wss_b = (const float*)d_in[4];
  const float* Wsy_w = (const float*)d_in[5];
  const float* Wsy_b = (const float*)d_in[6];
  float* y = (float*)d_out;
  char* ws = (char*)d_ws;

  u16*   xhi   = (u16*)(ws + OFF_XHI);
  u16*   xlo   = (u16*)(ws + OFF_XLO);
  u16*   whi   = (u16*)(ws + OFF_WHI);
  u16*   wlo   = (u16*)(ws + OFF_WLO);
  u16*   wsyb  = (u16*)(ws + OFF_WSY);
  float* xproj = (float*)(ws + OFF_XPROJ);
  u16*   hsb   = (u16*)(ws + OFF_HS);

  k0_convert<<<(NX + NW + NP) / 256, 256, 0, stream>>>(x, Wxs_w, Wsy_w, xhi, xlo, whi, wlo, wsyb);
  k1_xproj<<<128, 256, 0, stream>>>(xhi, xlo, whi, wlo, Wxs_b, xproj);
  k2_scan<<<16, 256, 0, stream>>>(xproj, Wss_w, Wss_b, hsb);
  k3_y<<<64 * 79, 256, 0, stream>>>(hsb, wsyb, Wsy_b, y);
}